// Round 10
// baseline (272.928 us; speedup 1.0000x reference)
//
#include <hip/hip_runtime.h>
#include <hip/hip_bf16.h>

// MHA layer: B=4, S=2048, D=1024, H=16, HD=64.
// Pipeline: cvt(f32->bf16) -> QKV proj GEMMs (bf16 MFMA) -> flash attn -> out proj.
// Mask handling: softmax is shift-invariant per row, so uniform mask rows (incl. the
// common all-zero / padding case) cancel EXACTLY -> precompute per-row uniformity
// flags and skip all mask loads on the fast path.

typedef float f32x4 __attribute__((ext_vector_type(4)));
typedef float f32x16 __attribute__((ext_vector_type(16)));
typedef short bf16x8 __attribute__((ext_vector_type(8)));

#define LOG2E 1.4426950408889634f

__device__ __forceinline__ void gload_lds16(const void* g, void* l) {
  __builtin_amdgcn_global_load_lds((const __attribute__((address_space(1))) void*)g,
                                   (__attribute__((address_space(3))) void*)l,
                                   16, 0, 0);
}

__device__ __forceinline__ float fast_exp2(float x) {
#if __has_builtin(__builtin_amdgcn_exp2f)
  return __builtin_amdgcn_exp2f(x);
#else
  return exp2f(x);
#endif
}

// packed bf16 convert: lo16 = bf16(a), hi16 = bf16(b)  (RNE, 1 inst)
__device__ __forceinline__ unsigned cvt_pk_bf16(float a, float b) {
  unsigned r;
  asm("v_cvt_pk_bf16_f32 %0, %1, %2" : "=v"(r) : "v"(a), "v"(b));
  return r;
}

// permlane32_swap: a' = [a(0..31), b(0..31)], b' = [a(32..63), b(32..63)]
__device__ __forceinline__ void pl32swap(unsigned& a, unsigned& b, int hi) {
#if __has_builtin(__builtin_amdgcn_permlane32_swap)
  typedef unsigned uint2v __attribute__((ext_vector_type(2)));
  uint2v r = __builtin_amdgcn_permlane32_swap(a, b, false, false);
  a = r[0];
  b = r[1];
#else
  unsigned ax = __shfl_xor((int)a, 32);
  unsigned bx = __shfl_xor((int)b, 32);
  unsigned na = hi ? bx : a;
  unsigned nb = hi ? b : ax;
  a = na;
  b = nb;
#endif
}

// swizzled LDS read of 16B: tile rows are 128B; XOR row-low-bits into the 16B-slot index
__device__ __forceinline__ bf16x8 lds_read_swz(const __hip_bfloat16* base, int row, int colByte) {
  int off = row * 128 + (colByte ^ ((row & 7) << 4));
  return *(const bf16x8*)((const char*)base + off);
}

// ---------------- f32 -> bf16 conversion ----------------
__global__ __launch_bounds__(256) void cvt3(const float* __restrict__ s0,
                                            const float* __restrict__ s1,
                                            const float* __restrict__ s2,
                                            __hip_bfloat16* __restrict__ d0,
                                            __hip_bfloat16* __restrict__ d1,
                                            __hip_bfloat16* __restrict__ d2, int n) {
  const float* s = blockIdx.z == 0 ? s0 : (blockIdx.z == 1 ? s1 : s2);
  __hip_bfloat16* d = blockIdx.z == 0 ? d0 : (blockIdx.z == 1 ? d1 : d2);
  int i = (blockIdx.x * 256 + threadIdx.x) * 8;
  if (i + 8 <= n) {
    float4 x = *(const float4*)(s + i);
    float4 y = *(const float4*)(s + i + 4);
    bf16x8 v;
    __hip_bfloat16* hv = (__hip_bfloat16*)&v;
    hv[0] = __float2bfloat16(x.x); hv[1] = __float2bfloat16(x.y);
    hv[2] = __float2bfloat16(x.z); hv[3] = __float2bfloat16(x.w);
    hv[4] = __float2bfloat16(y.x); hv[5] = __float2bfloat16(y.y);
    hv[6] = __float2bfloat16(y.z); hv[7] = __float2bfloat16(y.w);
    *(bf16x8*)(d + i) = v;
  }
}

__global__ __launch_bounds__(256) void cvt4(const float* __restrict__ s0,
                                            const float* __restrict__ s1,
                                            const float* __restrict__ s2,
                                            const float* __restrict__ s3,
                                            __hip_bfloat16* __restrict__ d0,
                                            __hip_bfloat16* __restrict__ d1,
                                            __hip_bfloat16* __restrict__ d2,
                                            __hip_bfloat16* __restrict__ d3, int n) {
  const float* s = blockIdx.z == 0 ? s0 : (blockIdx.z == 1 ? s1 : (blockIdx.z == 2 ? s2 : s3));
  __hip_bfloat16* d = blockIdx.z == 0 ? d0 : (blockIdx.z == 1 ? d1 : (blockIdx.z == 2 ? d2 : d3));
  int i = (blockIdx.x * 256 + threadIdx.x) * 8;
  if (i + 8 <= n) {
    float4 x = *(const float4*)(s + i);
    float4 y = *(const float4*)(s + i + 4);
    bf16x8 v;
    __hip_bfloat16* hv = (__hip_bfloat16*)&v;
    hv[0] = __float2bfloat16(x.x); hv[1] = __float2bfloat16(x.y);
    hv[2] = __float2bfloat16(x.z); hv[3] = __float2bfloat16(x.w);
    hv[4] = __float2bfloat16(y.x); hv[5] = __float2bfloat16(y.y);
    hv[6] = __float2bfloat16(y.z); hv[7] = __float2bfloat16(y.w);
    *(bf16x8*)(d + i) = v;
  }
}

// ---------------- mask row-uniformity flags ----------------
// One wave per (b,q) row; flag=1 iff all 2048 values equal. grid 2048 x block 256.
__global__ __launch_bounds__(256) void maskrow(const float* __restrict__ m,
                                               unsigned char* __restrict__ flags) {
  int row = blockIdx.x * 4 + (threadIdx.x >> 6);
  int l = threadIdx.x & 63;
  const float* r = m + (size_t)row * 2048;
  float v0 = r[0];
  bool eq = true;
#pragma unroll
  for (int i = 0; i < 8; i++) {
    float4 x = *(const float4*)(r + l * 4 + i * 256);
    eq &= (x.x == v0) & (x.y == v0) & (x.z == v0) & (x.w == v0);
  }
  unsigned long long b = __ballot((int)eq);
  if (l == 0) flags[row] = (b == ~0ull) ? 1 : 0;
}

// ---------------- GEMM: C = (A(8192x1024) * W(1024x1024)^T + bias) * scale ----------------
// MODE 0: bf16 out, row-major (M x 1024)
// MODE 1: bf16 out, transposed head layout vT[(b*16+h)*64+hd][s]  (V projection)
// MODE 2: f32 out, row-major (final output)
template <int MODE>
__global__ __launch_bounds__(256) void gemm_nt(const __hip_bfloat16* __restrict__ A,
                                               const __hip_bfloat16* __restrict__ W,
                                               const float* __restrict__ bias,
                                               void* __restrict__ out, float scale) {
  extern __shared__ char smem[];
  __hip_bfloat16(*As)[64] = (__hip_bfloat16(*)[64])smem;
  __hip_bfloat16(*Bs)[64] = (__hip_bfloat16(*)[64])(smem + 128 * 64 * 2);

  const int t = threadIdx.x;
  const int w = t >> 6, l = t & 63;
  const int wm = w >> 1, wn = w & 1;
  const int rowbase = blockIdx.y * 128;
  const int colbase = blockIdx.x * 128;
  const int lr = l & 15, lg = l >> 4;
  const int srow = l >> 3, schunk = (l & 7) * 8;

  f32x4 acc[4][4];
#pragma unroll
  for (int m = 0; m < 4; m++)
#pragma unroll
    for (int n = 0; n < 4; n++) acc[m][n] = {0.f, 0.f, 0.f, 0.f};

  for (int kt = 0; kt < 16; ++kt) {
    const int k0 = kt * 64;
#pragma unroll
    for (int i = 0; i < 4; i++) {
      int r = w * 32 + i * 8;
      gload_lds16(A + (size_t)(rowbase + r + srow) * 1024 + k0 + schunk, &As[r][0]);
      gload_lds16(W + (size_t)(colbase + r + srow) * 1024 + k0 + schunk, &Bs[r][0]);
    }
    __syncthreads();
#pragma unroll
    for (int kk = 0; kk < 2; kk++) {
      bf16x8 a[4], b[4];
#pragma unroll
      for (int m = 0; m < 4; m++) a[m] = *(const bf16x8*)&As[wm * 64 + m * 16 + lr][kk * 32 + lg * 8];
#pragma unroll
      for (int n = 0; n < 4; n++) b[n] = *(const bf16x8*)&Bs[wn * 64 + n * 16 + lr][kk * 32 + lg * 8];
#pragma unroll
      for (int m = 0; m < 4; m++)
#pragma unroll
        for (int n = 0; n < 4; n++)
          acc[m][n] = __builtin_amdgcn_mfma_f32_16x16x32_bf16(a[m], b[n], acc[m][n], 0, 0, 0);
    }
    __syncthreads();
  }

  if (MODE == 0 || MODE == 2) {
#pragma unroll
    for (int m = 0; m < 4; m++) {
#pragma unroll
      for (int r = 0; r < 4; r++) {
        int gi = rowbase + wm * 64 + m * 16 + lg * 4 + r;
#pragma unroll
        for (int n = 0; n < 4; n++) {
          int gj = colbase + wn * 64 + n * 16 + lr;
          float v = (acc[m][n][r] + bias[gj]) * scale;
          if (MODE == 0)
            ((__hip_bfloat16*)out)[(size_t)gi * 1024 + gj] = __float2bfloat16(v);
          else
            ((float*)out)[(size_t)gi * 1024 + gj] = v;
        }
      }
    }
  } else {
    // transpose epilogue: write vT[(b*16+h)*64+hd][s]
    __hip_bfloat16* Ts = (__hip_bfloat16*)smem;  // [128][130]
#pragma unroll
    for (int m = 0; m < 4; m++)
#pragma unroll
      for (int r = 0; r < 4; r++) {
        int rr = wm * 64 + m * 16 + lg * 4 + r;  // s within tile
#pragma unroll
        for (int n = 0; n < 4; n++) {
          int c = wn * 64 + n * 16 + lr;  // d within tile
          Ts[rr * 130 + c] = __float2bfloat16(acc[m][n][r] + bias[colbase + c]);
        }
      }
    __syncthreads();
    int d = t >> 1, s0 = (t & 1) * 64;
    int gd = colbase + d;
    int h = gd >> 6, hd = gd & 63;
    int gs = rowbase + s0;
    int b = gs >> 11, sl = gs & 2047;
    __hip_bfloat16* dst = (__hip_bfloat16*)out + ((size_t)(b * 16 + h) * 64 + hd) * 2048 + sl;
#pragma unroll
    for (int c8 = 0; c8 < 8; c8++) {
      bf16x8 v;
#pragma unroll
      for (int j = 0; j < 8; j++)
        ((unsigned short*)&v)[j] = ((const unsigned short*)Ts)[(s0 + c8 * 8 + j) * 130 + d];
      *(bf16x8*)(dst + c8 * 8) = v;
    }
  }
}

// ---------------- Flash attention (swapped QK^T, 32x32 MFMA, in-register P) ----------------
// grid (16, 64) = 1024 blocks = exactly 4/CU, LB(256,4) -> all co-resident, one round.
// Q pre-scaled by 0.125*LOG2E at projection. Uniform mask rows cancel in softmax ->
// fast path does ZERO mask work; non-uniform rows load f32 mask into the MFMA C-init.
// Row-sum computed on the MFMA pipe: psum += P_frag x ones (lands in acco's row layout,
// so rescale merges with acco's loop and no end-of-kernel shuffles are needed).
// P packed to bf16 with v_cvt_pk_bf16_f32 (1 inst / 2 elems).
__global__ __launch_bounds__(256, 4) void attn(const __hip_bfloat16* __restrict__ Q,
                                               const __hip_bfloat16* __restrict__ K,
                                               const __hip_bfloat16* __restrict__ Vt,
                                               const float* __restrict__ mask,
                                               const unsigned char* __restrict__ flags,
                                               __hip_bfloat16* __restrict__ O) {
  __shared__ __hip_bfloat16 Ks[2][64][64];
  __shared__ __hip_bfloat16 Vs[2][64][64];  // V^T tile: [hd][s_local]

  const int t = threadIdx.x, w = t >> 6, l = t & 63;
  const int l31 = l & 31, hi = l >> 5;
  // XCD-aware swizzle: 1024 blocks -> each XCD handles 8 consecutive bh (same b)
  int lin = blockIdx.y * 16 + blockIdx.x;
  lin = (lin & 7) * 128 + (lin >> 3);
  const int qt = lin & 15, bh = lin >> 4;
  const int b = bh >> 4, h = bh & 15;
  const int q0 = qt * 128 + w * 32;
  const size_t bS = (size_t)b * 2048;
  const int srow = l >> 3;
  const int swchunk = ((l & 7) * 8) ^ (srow << 3);  // inverse-swizzled source chunk (elems)

#define STAGE(dbuf, ktile)                                                             \
  do {                                                                                 \
    int kb_ = (ktile) * 64;                                                            \
    _Pragma("unroll") for (int i_ = 0; i_ < 2; i_++) {                                 \
      int r_ = w * 16 + i_ * 8;                                                        \
      gload_lds16(K + (bS + kb_ + r_ + srow) * 1024 + h * 64 + swchunk,                \
                  &Ks[dbuf][r_][0]);                                                   \
      gload_lds16(Vt + ((size_t)bh * 64 + r_ + srow) * 2048 + kb_ + swchunk,           \
                  &Vs[dbuf][r_][0]);                                                   \
    }                                                                                  \
  } while (0)

  // Q fragment (B operand): col=lane&31=q, k-slot=(lane>>5)*8+j; 4 hd-chunks of 16
  bf16x8 qf[4];
#pragma unroll
  for (int c = 0; c < 4; c++)
    qf[c] = *(const bf16x8*)(Q + (bS + q0 + l31) * 1024 + h * 64 + c * 16 + hi * 8);

  // all-ones bf16 fragment (B operand) for the row-sum MFMA
  bf16x8 vones;
#pragma unroll
  for (int j = 0; j < 8; j++) ((unsigned short*)&vones)[j] = 0x3F80;

  f32x16 acco[2], psum;
#pragma unroll
  for (int i = 0; i < 16; i++) { acco[0][i] = 0.f; acco[1][i] = 0.f; psum[i] = 0.f; }
  float m2 = -1e30f;

  // uniform-row flags: softmax(x + c) == softmax(x) for row-uniform mask -> skip mask.
  const bool need_mask = !__all((int)(flags[bS + q0 + l31] != 0));
  const float* mrowf = mask + (bS + q0 + l31) * 2048;

  STAGE(0, 0);
  __syncthreads();
  int cur = 0;

  for (int kt = 0; kt < 32; ++kt) {
    const int kb = kt * 64;
    if (kt < 31) STAGE(cur ^ 1, kt + 1);  // prefetch next K/V tile (completes at barrier)

    // C-init: zero (fast path) or mask*LOG2E (non-uniform rows).
    // acc reg r of half ks holds k = ks*32 + (r&3) + 8*(r>>2) + 4*hi, row q = l31.
    f32x16 sc[2];
    if (need_mask) {
#pragma unroll
      for (int ks = 0; ks < 2; ks++)
#pragma unroll
        for (int g = 0; g < 4; g++) {
          float4 tmp = *(const float4*)(mrowf + kb + ks * 32 + g * 8 + hi * 4);
          sc[ks][g * 4 + 0] = tmp.x * LOG2E; sc[ks][g * 4 + 1] = tmp.y * LOG2E;
          sc[ks][g * 4 + 2] = tmp.z * LOG2E; sc[ks][g * 4 + 3] = tmp.w * LOG2E;
        }
    } else {
#pragma unroll
      for (int i = 0; i < 16; i++) { sc[0][i] = 0.f; sc[1][i] = 0.f; }
    }

    // QK^T swapped: S[k][q] = sum_hd K[k][hd] * Q'[q][hd]   (Q' pre-scaled)
    __builtin_amdgcn_s_setprio(1);
#pragma unroll
    for (int c = 0; c < 4; c++) {
      bf16x8 ka0 = lds_read_swz(&Ks[cur][0][0], l31, c * 32 + hi * 16);
      sc[0] = __builtin_amdgcn_mfma_f32_32x32x16_bf16(ka0, qf[c], sc[0], 0, 0, 0);
      bf16x8 ka1 = lds_read_swz(&Ks[cur][0][0], 32 + l31, c * 32 + hi * 16);
      sc[1] = __builtin_amdgcn_mfma_f32_32x32x16_bf16(ka1, qf[c], sc[1], 0, 0, 0);
    }
    __builtin_amdgcn_s_setprio(0);

    // row-max: tree over lane's 32 values + one cross-half exchange
    float mx[16];
#pragma unroll
    for (int r = 0; r < 16; r++) mx[r] = fmaxf(sc[0][r], sc[1][r]);
#pragma unroll
    for (int s = 8; s >= 1; s >>= 1)
#pragma unroll
      for (int r = 0; r < s; r++) mx[r] = fmaxf(mx[r], mx[r + s]);
    float tmax = fmaxf(mx[0], __shfl_xor(mx[0], 32));

    // defer-max (T13): rescale only when running max grew by > 8 (log2 domain)
    if (__any(tmax > m2 + 8.0f)) {
      float mn = fmaxf(m2, tmax);
      float rs = fast_exp2(m2 - mn);
      m2 = mn;
#pragma unroll
      for (int r = 0; r < 16; r++) {
        float rsr = __shfl(rs, (r & 3) + 8 * (r >> 2) + 4 * hi);
        psum[r] *= rsr;
        acco[0][r] *= rsr;
        acco[1][r] *= rsr;
      }
    }

    // p = exp2(sc - m2), pack to bf16 pairs via cvt_pk (k ascending within pair).
    // Row-sum comes from the ones-MFMA below (denominator sums the same bf16 P
    // values as the numerator -> consistent).
    unsigned pk[2][4][2];
#pragma unroll
    for (int ks = 0; ks < 2; ks++)
#pragma unroll
      for (int g = 0; g < 4; g++)
#pragma unroll
        for (int s = 0; s < 2; s++) {
          float p0 = fast_exp2(sc[ks][g * 4 + s * 2] - m2);
          float p1 = fast_exp2(sc[ks][g * 4 + s * 2 + 1] - m2);
          pk[ks][g][s] = cvt_pk_bf16(p0, p1);
        }

    // PV: A = P[q][k] via permlane32_swap redistribution; B = V from LDS.
    // psum += P x ones on the MFMA pipe (replaces the VALU sum tree).
    __builtin_amdgcn_s_setprio(1);
#pragma unroll
    for (int ks = 0; ks < 2; ks++) {
#pragma unroll
      for (int c16 = 0; c16 < 2; c16++) {
        unsigned x0 = pk[ks][2 * c16][0], y0 = pk[ks][2 * c16 + 1][0];
        unsigned x1 = pk[ks][2 * c16][1], y1 = pk[ks][2 * c16 + 1][1];
        pl32swap(x0, y0, hi);
        pl32swap(x1, y1, hi);
        bf16x8 pa;
        ((unsigned*)&pa)[0] = x0; ((unsigned*)&pa)[1] = x1;
        ((unsigned*)&pa)[2] = y0; ((unsigned*)&pa)[3] = y1;
        psum = __builtin_amdgcn_mfma_f32_32x32x16_bf16(pa, vones, psum, 0, 0, 0);
#pragma unroll
        for (int ds = 0; ds < 2; ds++) {
          bf16x8 vb = lds_read_swz(&Vs[cur][0][0], ds * 32 + l31, ks * 64 + c16 * 32 + hi * 16);
          acco[ds] = __builtin_amdgcn_mfma_f32_32x32x16_bf16(pa, vb, acco[ds], 0, 0, 0);
        }
      }
    }
    __builtin_amdgcn_s_setprio(0);
    __syncthreads();  // drains prefetch vmcnt + releases read buffer
    cur ^= 1;
  }
#undef STAGE

  // epilogue: O[q][d], q = q0 + (r&3)+8*(r>>2)+4*hi, d = ds*32 + l31
  // psum[r] is the row-sum for the same q as acco[*][r] -> no shuffles needed.
#pragma unroll
  for (int r = 0; r < 16; r++) {
    float invr = 1.0f / psum[r];
    int q = q0 + (r & 3) + 8 * (r >> 2) + 4 * hi;
#pragma unroll
    for (int ds = 0; ds < 2; ds++)
      O[(bS + q) * 1024 + h * 64 + ds * 32 + l31] = __float2bfloat16(acco[ds][r] * invr);
  }
}

extern "C" void kernel_launch(void* const* d_in, const int* in_sizes, int n_in,
                              void* d_out, int out_size, void* d_ws, size_t ws_size,
                              hipStream_t stream) {
  const float* q = (const float*)d_in[0];
  const float* k = (const float*)d_in[1];
  const float* v = (const float*)d_in[2];
  const float* msk = (const float*)d_in[3];
  const float* Wq = (const float*)d_in[4];
  const float* bq = (const float*)d_in[5];
  const float* Wk = (const float*)d_in[6];
  const float* bk = (const float*)d_in[7];
  const float* Wv = (const float*)d_in[8];
  const float* bv = (const float*)d_in[9];
  const float* Wo = (const float*)d_in[10];
  const float* bo = (const float*)d_in[11];

  // workspace layout (buffers reused once freed):
  char* ws = (char*)d_ws;
  __hip_bfloat16* qin = (__hip_bfloat16*)(ws);                       // [0,16M)
  __hip_bfloat16* kin = (__hip_bfloat16*)(ws + (16u << 20));         // [16,32M)
  __hip_bfloat16* vin = (__hip_bfloat16*)(ws + (32u << 20));         // [32,48M)
  __hip_bfloat16* wqb = (__hip_bfloat16*)(ws + (48u << 20));
  __hip_bfloat16* wkb = (__hip_bfloat16*)(ws + (50u << 20));
  __hip_bfloat16* wvb = (__hip_bfloat16*)(ws + (52u << 20));
  __hip_bfloat16* wob = (__hip_bfloat16*)(ws + (54u << 20));
  __hip_bfloat16* vT  = (__hip_bfloat16*)(ws + (56u << 20));         // [56,72M)
  unsigned char* flags = (unsigned char*)(ws + (72u << 20));         // [72M, +8KB)
  __hip_bfloat16* kp  = vin;  // vin free after V-proj
  __hip_bfloat16* qp  = kin;  // kin free after K-proj
  __hip_bfloat16* oat = qin;  // qin free after Q-proj

  dim3 blk(256);
  size_t smem = 33280;  // max(2*128*64*2, 128*130*2)
  const float qscale = 0.125f * LOG2E;  // folded into Q projection output

  cvt3<<<dim3(4096, 1, 3), blk, 0, stream>>>(q, k, v, qin, kin, vin, 8388608);
  cvt4<<<dim3(512, 1, 4), blk, 0, stream>>>(Wq, Wk, Wv, Wo, wqb, wkb, wvb, wob, 1048576);
  maskrow<<<dim3(2048), blk, 0, stream>>>(msk, flags);
  gemm_nt<1><<<dim3(8, 64), blk, smem, stream>>>(vin, wvb, bv, vT, 1.0f);
  gemm_nt<0><<<dim3(8, 64), blk, smem, stream>>>(kin, wkb, bk, kp, 1.0f);
  gemm_nt<0><<<dim3(8, 64), blk, smem, stream>>>(qin, wqb, bq, qp, qscale);
  attn<<<dim3(16, 64), blk, 0, stream>>>(qp, kp, vT, msk, flags, oat);
  gemm_nt<2><<<dim3(8, 64), blk, smem, stream>>>(oat, wob, bo, (float*)d_out, 1.0f);
}

// Round 12
// 268.426 us; speedup vs baseline: 1.0168x; 1.0168x over previous
//
#include <hip/hip_runtime.h>
#include <hip/hip_bf16.h>

// MHA layer: B=4, S=2048, D=1024, H=16, HD=64.
// Pipeline: cvt(f32->bf16) -> merged QKV proj GEMM (grid.z=3) -> flash attn -> out proj.
// Mask handling: softmax is shift-invariant per row, so uniform mask rows cancel
// EXACTLY -> per-row uniformity flags; fast path does zero mask work.

typedef float f32x4 __attribute__((ext_vector_type(4)));
typedef float f32x16 __attribute__((ext_vector_type(16)));
typedef short bf16x8 __attribute__((ext_vector_type(8)));

#define LOG2E 1.4426950408889634f

__device__ __forceinline__ void gload_lds16(const void* g, void* l) {
  __builtin_amdgcn_global_load_lds((const __attribute__((address_space(1))) void*)g,
                                   (__attribute__((address_space(3))) void*)l,
                                   16, 0, 0);
}

__device__ __forceinline__ float fast_exp2(float x) {
#if __has_builtin(__builtin_amdgcn_exp2f)
  return __builtin_amdgcn_exp2f(x);
#else
  return exp2f(x);
#endif
}

// packed bf16 convert: lo16 = bf16(a), hi16 = bf16(b)  (RNE, 1 inst)
__device__ __forceinline__ unsigned cvt_pk_bf16(float a, float b) {
  unsigned r;
  asm("v_cvt_pk_bf16_f32 %0, %1, %2" : "=v"(r) : "v"(a), "v"(b));
  return r;
}

// permlane32_swap: a' = [a(0..31), b(0..31)], b' = [a(32..63), b(32..63)]
__device__ __forceinline__ void pl32swap(unsigned& a, unsigned& b, int hi) {
#if __has_builtin(__builtin_amdgcn_permlane32_swap)
  typedef unsigned uint2v __attribute__((ext_vector_type(2)));
  uint2v r = __builtin_amdgcn_permlane32_swap(a, b, false, false);
  a = r[0];
  b = r[1];
#else
  unsigned ax = __shfl_xor((int)a, 32);
  unsigned bx = __shfl_xor((int)b, 32);
  unsigned na = hi ? bx : a;
  unsigned nb = hi ? b : ax;
  a = na;
  b = nb;
#endif
}

// swizzled LDS read of 16B: tile rows are 128B; XOR row-low-bits into the 16B-slot index
__device__ __forceinline__ bf16x8 lds_read_swz(const __hip_bfloat16* base, int row, int colByte) {
  int off = row * 128 + (colByte ^ ((row & 7) << 4));
  return *(const bf16x8*)((const char*)base + off);
}

// ---------------- f32 -> bf16 conversion ----------------
__global__ __launch_bounds__(256) void cvt3(const float* __restrict__ s0,
                                            const float* __restrict__ s1,
                                            const float* __restrict__ s2,
                                            __hip_bfloat16* __restrict__ d0,
                                            __hip_bfloat16* __restrict__ d1,
                                            __hip_bfloat16* __restrict__ d2, int n) {
  const float* s = blockIdx.z == 0 ? s0 : (blockIdx.z == 1 ? s1 : s2);
  __hip_bfloat16* d = blockIdx.z == 0 ? d0 : (blockIdx.z == 1 ? d1 : d2);
  int i = (blockIdx.x * 256 + threadIdx.x) * 8;
  if (i + 8 <= n) {
    float4 x = *(const float4*)(s + i);
    float4 y = *(const float4*)(s + i + 4);
    bf16x8 v;
    __hip_bfloat16* hv = (__hip_bfloat16*)&v;
    hv[0] = __float2bfloat16(x.x); hv[1] = __float2bfloat16(x.y);
    hv[2] = __float2bfloat16(x.z); hv[3] = __float2bfloat16(x.w);
    hv[4] = __float2bfloat16(y.x); hv[5] = __float2bfloat16(y.y);
    hv[6] = __float2bfloat16(y.z); hv[7] = __float2bfloat16(y.w);
    *(bf16x8*)(d + i) = v;
  }
}

__global__ __launch_bounds__(256) void cvt4(const float* __restrict__ s0,
                                            const float* __restrict__ s1,
                                            const float* __restrict__ s2,
                                            const float* __restrict__ s3,
                                            __hip_bfloat16* __restrict__ d0,
                                            __hip_bfloat16* __restrict__ d1,
                                            __hip_bfloat16* __restrict__ d2,
                                            __hip_bfloat16* __restrict__ d3, int n) {
  const float* s = blockIdx.z == 0 ? s0 : (blockIdx.z == 1 ? s1 : (blockIdx.z == 2 ? s2 : s3));
  __hip_bfloat16* d = blockIdx.z == 0 ? d0 : (blockIdx.z == 1 ? d1 : (blockIdx.z == 2 ? d2 : d3));
  int i = (blockIdx.x * 256 + threadIdx.x) * 8;
  if (i + 8 <= n) {
    float4 x = *(const float4*)(s + i);
    float4 y = *(const float4*)(s + i + 4);
    bf16x8 v;
    __hip_bfloat16* hv = (__hip_bfloat16*)&v;
    hv[0] = __float2bfloat16(x.x); hv[1] = __float2bfloat16(x.y);
    hv[2] = __float2bfloat16(x.z); hv[3] = __float2bfloat16(x.w);
    hv[4] = __float2bfloat16(y.x); hv[5] = __float2bfloat16(y.y);
    hv[6] = __float2bfloat16(y.z); hv[7] = __float2bfloat16(y.w);
    *(bf16x8*)(d + i) = v;
  }
}

// ---------------- mask row-uniformity flags ----------------
// One wave per (b,q) row; flag=1 iff all 2048 values equal. grid 2048 x block 256.
__global__ __launch_bounds__(256) void maskrow(const float* __restrict__ m,
                                               unsigned char* __restrict__ flags) {
  int row = blockIdx.x * 4 + (threadIdx.x >> 6);
  int l = threadIdx.x & 63;
  const float* r = m + (size_t)row * 2048;
  float v0 = r[0];
  bool eq = true;
#pragma unroll
  for (int i = 0; i < 8; i++) {
    float4 x = *(const float4*)(r + l * 4 + i * 256);
    eq &= (x.x == v0) & (x.y == v0) & (x.z == v0) & (x.w == v0);
  }
  unsigned long long b = __ballot((int)eq);
  if (l == 0) flags[row] = (b == ~0ull) ? 1 : 0;
}

// ---------------- GEMM main-loop body (shared) ----------------
// Computes acc[4][4] for C-tile (rowbase,colbase) of A(8192x1024) * W(1024x1024)^T.
__device__ __forceinline__ void gemm_core(const __hip_bfloat16* __restrict__ A,
                                          const __hip_bfloat16* __restrict__ W,
                                          char* smem, int rowbase, int colbase,
                                          f32x4 acc[4][4]) {
  __hip_bfloat16(*As)[64] = (__hip_bfloat16(*)[64])smem;
  __hip_bfloat16(*Bs)[64] = (__hip_bfloat16(*)[64])(smem + 128 * 64 * 2);
  const int t = threadIdx.x;
  const int w = t >> 6, l = t & 63;
  const int wm = w >> 1, wn = w & 1;
  const int lr = l & 15, lg = l >> 4;
  const int srow = l >> 3, schunk = (l & 7) * 8;

#pragma unroll
  for (int m = 0; m < 4; m++)
#pragma unroll
    for (int n = 0; n < 4; n++) acc[m][n] = {0.f, 0.f, 0.f, 0.f};

  for (int kt = 0; kt < 16; ++kt) {
    const int k0 = kt * 64;
#pragma unroll
    for (int i = 0; i < 4; i++) {
      int r = w * 32 + i * 8;
      gload_lds16(A + (size_t)(rowbase + r + srow) * 1024 + k0 + schunk, &As[r][0]);
      gload_lds16(W + (size_t)(colbase + r + srow) * 1024 + k0 + schunk, &Bs[r][0]);
    }
    __syncthreads();
#pragma unroll
    for (int kk = 0; kk < 2; kk++) {
      bf16x8 a[4], b[4];
#pragma unroll
      for (int m = 0; m < 4; m++) a[m] = *(const bf16x8*)&As[wm * 64 + m * 16 + lr][kk * 32 + lg * 8];
#pragma unroll
      for (int n = 0; n < 4; n++) b[n] = *(const bf16x8*)&Bs[wn * 64 + n * 16 + lr][kk * 32 + lg * 8];
#pragma unroll
      for (int m = 0; m < 4; m++)
#pragma unroll
        for (int n = 0; n < 4; n++)
          acc[m][n] = __builtin_amdgcn_mfma_f32_16x16x32_bf16(a[m], b[n], acc[m][n], 0, 0, 0);
    }
    __syncthreads();
  }
}

// row-major store epilogue (bf16 or f32)
template <int F32OUT>
__device__ __forceinline__ void gemm_store_rows(f32x4 acc[4][4], const float* __restrict__ bias,
                                                void* __restrict__ out, int rowbase, int colbase,
                                                float scale) {
  const int l = threadIdx.x & 63, w = threadIdx.x >> 6;
  const int wm = w >> 1, wn = w & 1;
  const int lr = l & 15, lg = l >> 4;
#pragma unroll
  for (int m = 0; m < 4; m++)
#pragma unroll
    for (int r = 0; r < 4; r++) {
      int gi = rowbase + wm * 64 + m * 16 + lg * 4 + r;
#pragma unroll
      for (int n = 0; n < 4; n++) {
        int gj = colbase + wn * 64 + n * 16 + lr;
        float v = (acc[m][n][r] + bias[gj]) * scale;
        if (F32OUT)
          ((float*)out)[(size_t)gi * 1024 + gj] = v;
        else
          ((__hip_bfloat16*)out)[(size_t)gi * 1024 + gj] = __float2bfloat16(v);
      }
    }
}

// transpose epilogue: write vT[(b*16+h)*64+hd][s]
__device__ __forceinline__ void gemm_store_vT(f32x4 acc[4][4], const float* __restrict__ bias,
                                              __hip_bfloat16* __restrict__ out, char* smem,
                                              int rowbase, int colbase) {
  const int t = threadIdx.x, l = t & 63, w = t >> 6;
  const int wm = w >> 1, wn = w & 1;
  const int lr = l & 15, lg = l >> 4;
  __hip_bfloat16* Ts = (__hip_bfloat16*)smem;  // [128][130]
#pragma unroll
  for (int m = 0; m < 4; m++)
#pragma unroll
    for (int r = 0; r < 4; r++) {
      int rr = wm * 64 + m * 16 + lg * 4 + r;  // s within tile
#pragma unroll
      for (int n = 0; n < 4; n++) {
        int c = wn * 64 + n * 16 + lr;  // d within tile
        Ts[rr * 130 + c] = __float2bfloat16(acc[m][n][r] + bias[colbase + c]);
      }
    }
  __syncthreads();
  int d = t >> 1, s0 = (t & 1) * 64;
  int gd = colbase + d;
  int h = gd >> 6, hd = gd & 63;
  int gs = rowbase + s0;
  int b = gs >> 11, sl = gs & 2047;
  __hip_bfloat16* dst = out + ((size_t)(b * 16 + h) * 64 + hd) * 2048 + sl;
#pragma unroll
  for (int c8 = 0; c8 < 8; c8++) {
    bf16x8 v;
#pragma unroll
    for (int j = 0; j < 8; j++)
      ((unsigned short*)&v)[j] = ((const unsigned short*)Ts)[(s0 + c8 * 8 + j) * 130 + d];
    *(bf16x8*)(dst + c8 * 8) = v;
  }
}

// ---------------- merged Q/K/V projection GEMM (grid.z = 3) ----------------
// z=0: V -> vT (transpose layout), z=1: K -> kp, z=2: Q -> qp (pre-scaled).
// 1536 blocks total (vs 512/launch) -> 4 blocks/CU resident, hides the per-tile
// barrier drain that capped the sequential launches at 2 blocks/CU.
__global__ __launch_bounds__(256) void gemm_qkv(
    const __hip_bfloat16* __restrict__ vin, const __hip_bfloat16* __restrict__ kin,
    const __hip_bfloat16* __restrict__ qin, const __hip_bfloat16* __restrict__ wv,
    const __hip_bfloat16* __restrict__ wk, const __hip_bfloat16* __restrict__ wq,
    const float* __restrict__ bv, const float* __restrict__ bk, const float* __restrict__ bq,
    __hip_bfloat16* __restrict__ vT, __hip_bfloat16* __restrict__ kp,
    __hip_bfloat16* __restrict__ qp, float qscale) {
  extern __shared__ char smem[];
  const int z = blockIdx.z;
  const __hip_bfloat16* A = z == 0 ? vin : (z == 1 ? kin : qin);
  const __hip_bfloat16* W = z == 0 ? wv : (z == 1 ? wk : wq);
  const float* bias = z == 0 ? bv : (z == 1 ? bk : bq);
  const int rowbase = blockIdx.y * 128;
  const int colbase = blockIdx.x * 128;

  f32x4 acc[4][4];
  gemm_core(A, W, smem, rowbase, colbase, acc);

  if (z == 0) {
    gemm_store_vT(acc, bias, vT, smem, rowbase, colbase);
  } else {
    gemm_store_rows<0>(acc, bias, z == 1 ? (void*)kp : (void*)qp, rowbase, colbase,
                       z == 2 ? qscale : 1.0f);
  }
}

// ---------------- standalone GEMM (fallback path + output projection) ----------------
// MODE 0: bf16 out row-major; MODE 1: vT transpose; MODE 2: f32 out row-major
template <int MODE>
__global__ __launch_bounds__(256) void gemm_nt(const __hip_bfloat16* __restrict__ A,
                                               const __hip_bfloat16* __restrict__ W,
                                               const float* __restrict__ bias,
                                               void* __restrict__ out, float scale) {
  extern __shared__ char smem[];
  const int rowbase = blockIdx.y * 128;
  const int colbase = blockIdx.x * 128;
  f32x4 acc[4][4];
  gemm_core(A, W, smem, rowbase, colbase, acc);
  if (MODE == 1)
    gemm_store_vT(acc, bias, (__hip_bfloat16*)out, smem, rowbase, colbase);
  else if (MODE == 0)
    gemm_store_rows<0>(acc, bias, out, rowbase, colbase, scale);
  else
    gemm_store_rows<1>(acc, bias, out, rowbase, colbase, scale);
}

// ---------------- Flash attention (swapped QK^T, 32x32 MFMA, in-register P) ----------------
// grid (16, 64) = 1024 blocks = exactly 4/CU, LB(256,4) -> all co-resident, one round.
// Q pre-scaled by 0.125*LOG2E at projection. Uniform mask rows cancel in softmax ->
// fast path does ZERO mask work; non-uniform rows load f32 mask into the MFMA C-init.
// Row-sum on the MFMA pipe: psum += P_frag x ones (lands in acco's row layout).
// P packed to bf16 with v_cvt_pk_bf16_f32 (1 inst / 2 elems).
__global__ __launch_bounds__(256, 4) void attn(const __hip_bfloat16* __restrict__ Q,
                                               const __hip_bfloat16* __restrict__ K,
                                               const __hip_bfloat16* __restrict__ Vt,
                                               const float* __restrict__ mask,
                                               const unsigned char* __restrict__ flags,
                                               __hip_bfloat16* __restrict__ O) {
  __shared__ __hip_bfloat16 Ks[2][64][64];
  __shared__ __hip_bfloat16 Vs[2][64][64];  // V^T tile: [hd][s_local]

  const int t = threadIdx.x, w = t >> 6, l = t & 63;
  const int l31 = l & 31, hi = l >> 5;
  // XCD-aware swizzle: 1024 blocks -> each XCD handles 8 consecutive bh (same b)
  int lin = blockIdx.y * 16 + blockIdx.x;
  lin = (lin & 7) * 128 + (lin >> 3);
  const int qt = lin & 15, bh = lin >> 4;
  const int b = bh >> 4, h = bh & 15;
  const int q0 = qt * 128 + w * 32;
  const size_t bS = (size_t)b * 2048;
  const int srow = l >> 3;
  const int swchunk = ((l & 7) * 8) ^ (srow << 3);  // inverse-swizzled source chunk (elems)

#define STAGE(dbuf, ktile)                                                             \
  do {                                                                                 \
    int kb_ = (ktile) * 64;                                                            \
    _Pragma("unroll") for (int i_ = 0; i_ < 2; i_++) {                                 \
      int r_ = w * 16 + i_ * 8;                                                        \
      gload_lds16(K + (bS + kb_ + r_ + srow) * 1024 + h * 64 + swchunk,                \
                  &Ks[dbuf][r_][0]);                                                   \
      gload_lds16(Vt + ((size_t)bh * 64 + r_ + srow) * 2048 + kb_ + swchunk,           \
                  &Vs[dbuf][r_][0]);                                                   \
    }                                                                                  \
  } while (0)

  // Q fragment (B operand): col=lane&31=q, k-slot=(lane>>5)*8+j; 4 hd-chunks of 16
  bf16x8 qf[4];
#pragma unroll
  for (int c = 0; c < 4; c++)
    qf[c] = *(const bf16x8*)(Q + (bS + q0 + l31) * 1024 + h * 64 + c * 16 + hi * 8);

  // all-ones bf16 fragment (B operand) for the row-sum MFMA
  bf16x8 vones;
#pragma unroll
  for (int j = 0; j < 8; j++) ((unsigned short*)&vones)[j] = 0x3F80;

  f32x16 acco[2], psum;
#pragma unroll
  for (int i = 0; i < 16; i++) { acco[0][i] = 0.f; acco[1][i] = 0.f; psum[i] = 0.f; }
  float m2 = -1e30f;

  // uniform-row flags: softmax(x + c) == softmax(x) for row-uniform mask -> skip mask.
  const bool need_mask = !__all((int)(flags[bS + q0 + l31] != 0));
  const float* mrowf = mask + (bS + q0 + l31) * 2048;

  STAGE(0, 0);
  __syncthreads();
  int cur = 0;

  for (int kt = 0; kt < 32; ++kt) {
    const int kb = kt * 64;
    if (kt < 31) STAGE(cur ^ 1, kt + 1);  // prefetch next K/V tile (completes at barrier)

    // C-init: zero (fast path) or mask*LOG2E (non-uniform rows).
    // acc reg r of half ks holds k = ks*32 + (r&3) + 8*(r>>2) + 4*hi, row q = l31.
    f32x16 sc[2];
    if (need_mask) {
#pragma unroll
      for (int ks = 0; ks < 2; ks++)
#pragma unroll
        for (int g = 0; g < 4; g++) {
          float4 tmp = *(const float4*)(mrowf + kb + ks * 32 + g * 8 + hi * 4);
          sc[ks][g * 4 + 0] = tmp.x * LOG2E; sc[ks][g * 4 + 1] = tmp.y * LOG2E;
          sc[ks][g * 4 + 2] = tmp.z * LOG2E; sc[ks][g * 4 + 3] = tmp.w * LOG2E;
        }
    } else {
#pragma unroll
      for (int i = 0; i < 16; i++) { sc[0][i] = 0.f; sc[1][i] = 0.f; }
    }

    // QK^T swapped: S[k][q] = sum_hd K[k][hd] * Q'[q][hd]   (Q' pre-scaled)
    __builtin_amdgcn_s_setprio(1);
#pragma unroll
    for (int c = 0; c < 4; c++) {
      bf16x8 ka0 = lds_read_swz(&Ks[cur][0][0], l31, c * 32 + hi * 16);
      sc[0] = __builtin_amdgcn_mfma_f32_32x32x16_bf16(ka0, qf[c], sc[0], 0, 0, 0);
      bf16x8 ka1 = lds_read_swz(&Ks[cur][0][0], 32 + l31, c * 32 + hi * 16);
      sc[1] = __builtin_amdgcn_mfma_f32_32x32x16_bf16(ka1, qf[c], sc[1], 0, 0, 0);
    }
    __builtin_amdgcn_s_setprio(0);

    // row-max: tree over lane's 32 values + one cross-half exchange
    float mx[16];
#pragma unroll
    for (int r = 0; r < 16; r++) mx[r] = fmaxf(sc[0][r], sc[1][r]);
#pragma unroll
    for (int s = 8; s >= 1; s >>= 1)
#pragma unroll
      for (int r = 0; r < s; r++) mx[r] = fmaxf(mx[r], mx[r + s]);
    float tmax = fmaxf(mx[0], __shfl_xor(mx[0], 32));

    // defer-max (T13): rescale only when running max grew by > 8 (log2 domain)
    if (__any(tmax > m2 + 8.0f)) {
      float mn = fmaxf(m2, tmax);
      float rs = fast_exp2(m2 - mn);
      m2 = mn;
#pragma unroll
      for (int r = 0; r < 16; r++) {
        float rsr = __shfl(rs, (r & 3) + 8 * (r >> 2) + 4 * hi);
        psum[r] *= rsr;
        acco[0][r] *= rsr;
        acco[1][r] *= rsr;
      }
    }

    // p = exp2(sc - m2), pack to bf16 pairs via cvt_pk (k ascending within pair).
    unsigned pk[2][4][2];
#pragma unroll
    for (int ks = 0; ks < 2; ks++)
#pragma unroll
      for (int g = 0; g < 4; g++)
#pragma unroll
        for (int s = 0; s < 2; s++) {
          float p0 = fast_exp2(sc[ks][g * 4 + s * 2] - m2);
          float p1 = fast_exp2(sc[ks][g * 4 + s * 2 + 1] - m2);
          pk[ks][g][s] = cvt_pk_bf16(p0, p1);
        }

    // PV: A = P[q][k] via permlane32_swap redistribution; B = V from LDS.
    // psum += P x ones on the MFMA pipe (replaces the VALU sum tree).
    __builtin_amdgcn_s_setprio(1);
#pragma unroll
    for (int ks = 0; ks < 2; ks++) {
#pragma unroll
      for (int c16 = 0; c16 < 2; c16++) {
        unsigned x0 = pk[ks][2 * c16][0], y0 = pk[ks][2 * c16 + 1][0];
        unsigned x1 = pk[ks][2 * c16][1], y1 = pk[ks][2 * c16 + 1][1];
        pl32swap(x0, y0, hi);
        pl32swap(x1, y1, hi);
        bf16x8 pa;
        ((unsigned*)&pa)[0] = x0; ((unsigned*)&pa)[1] = x1;
        ((unsigned*)&pa)[2] = y0; ((unsigned*)&pa)[3] = y1;
        psum = __builtin_amdgcn_mfma_f32_32x32x16_bf16(pa, vones, psum, 0, 0, 0);
#pragma unroll
        for (int ds = 0; ds < 2; ds++) {
          bf16x8 vb = lds_read_swz(&Vs[cur][0][0], ds * 32 + l31, ks * 64 + c16 * 32 + hi * 16);
          acco[ds] = __builtin_amdgcn_mfma_f32_32x32x16_bf16(pa, vb, acco[ds], 0, 0, 0);
        }
      }
    }
    __builtin_amdgcn_s_setprio(0);
    __syncthreads();  // drains prefetch vmcnt + releases read buffer
    cur ^= 1;
  }
#undef STAGE

  // epilogue: O[q][d], q = q0 + (r&3)+8*(r>>2)+4*hi, d = ds*32 + l31
  // psum[r] is the row-sum for the same q as acco[*][r] -> no shuffles needed.
#pragma unroll
  for (int r = 0; r < 16; r++) {
    float invr = 1.0f / psum[r];
    int q = q0 + (r & 3) + 8 * (r >> 2) + 4 * hi;
#pragma unroll
    for (int ds = 0; ds < 2; ds++)
      O[(bS + q) * 1024 + h * 64 + ds * 32 + l31] = __float2bfloat16(acco[ds][r] * invr);
  }
}

extern "C" void kernel_launch(void* const* d_in, const int* in_sizes, int n_in,
                              void* d_out, int out_size, void* d_ws, size_t ws_size,
                              hipStream_t stream) {
  const float* q = (const float*)d_in[0];
  const float* k = (const float*)d_in[1];
  const float* v = (const float*)d_in[2];
  const float* msk = (const float*)d_in[3];
  const float* Wq = (const float*)d_in[4];
  const float* bq = (const float*)d_in[5];
  const float* Wk = (const float*)d_in[6];
  const float* bk = (const float*)d_in[7];
  const float* Wv = (const float*)d_in[8];
  const float* bv = (const float*)d_in[9];
  const float* Wo = (const float*)d_in[10];
  const float* bo = (const float*)d_in[11];

  // workspace layout:
  char* ws = (char*)d_ws;
  __hip_bfloat16* qin = (__hip_bfloat16*)(ws);                       // [0,16M)
  __hip_bfloat16* kin = (__hip_bfloat16*)(ws + (16u << 20));         // [16,32M)
  __hip_bfloat16* vin = (__hip_bfloat16*)(ws + (32u << 20));         // [32,48M)
  __hip_bfloat16* wqb = (__hip_bfloat16*)(ws + (48u << 20));
  __hip_bfloat16* wkb = (__hip_bfloat16*)(ws + (50u << 20));
  __hip_bfloat16* wvb = (__hip_bfloat16*)(ws + (52u << 20));
  __hip_bfloat16* wob = (__hip_bfloat16*)(ws + (54u << 20));
  __hip_bfloat16* vT  = (__hip_bfloat16*)(ws + (56u << 20));         // [56,72M)

  const bool merged = ws_size >= (104ull << 20) + 8192;

  dim3 blk(256);
  size_t smem = 33280;  // max(2*128*64*2, 128*130*2)
  const float qscale = 0.125f * LOG2E;  // folded into Q projection output

  cvt3<<<dim3(4096, 1, 3), blk, 0, stream>>>(q, k, v, qin, kin, vin, 8388608);
  cvt4<<<dim3(512, 1, 4), blk, 0, stream>>>(Wq, Wk, Wv, Wo, wqb, wkb, wvb, wob, 1048576);

  if (merged) {
    // independent outputs -> one dispatch, 1536 blocks (4/CU resident)
    __hip_bfloat16* kp = (__hip_bfloat16*)(ws + (72u << 20));        // [72,88M)
    __hip_bfloat16* qp = (__hip_bfloat16*)(ws + (88u << 20));        // [88,104M)
    unsigned char* flags = (unsigned char*)(ws + (104u << 20));      // [104M,+8KB)
    __hip_bfloat16* oat = qin;  // qin free after merged GEMM
    maskrow<<<dim3(2048), blk, 0, stream>>>(msk, flags);
    gemm_qkv<<<dim3(8, 64, 3), blk, smem, stream>>>(vin, kin, qin, wvb, wkb, wqb,
                                                    bv, bk, bq, vT, kp, qp, qscale);
    attn<<<dim3(16, 64), blk, 0, stream>>>(qp, kp, vT, msk, flags, oat);
    gemm_nt<2><<<dim3(8, 64), blk, smem, stream>>>(oat, wob, bo, (float*)d_out, 1.0f);
  } else {
    // sequential fallback (aliased buffers, as R8)
    __hip_bfloat16* kp = vin;   // vin free after V-proj
    __hip_bfloat16* qp = kin;   // kin free after K-proj
    unsigned char* flags = (unsigned char*)(ws + (72u << 20));
    __hip_bfloat16* oat = qin;  // qin free after Q-proj
    maskrow<<<dim3(2048), blk, 0, stream>>>(msk, flags);
    gemm_nt<1><<<dim3(8, 64), blk, smem, stream>>>(vin, wvb, bv, vT, 1.0f);
    gemm_nt<0><<<dim3(8, 64), blk, smem, stream>>>(kin, wkb, bk, kp, 1.0f);
    gemm_nt<0><<<dim3(8, 64), blk, smem, stream>>>(qin, wqb, bq, qp, qscale);
    attn<<<dim3(16, 64), blk, 0, stream>>>(qp, kp, vT, msk, flags, oat);
    gemm_nt<2><<<dim3(8, 64), blk, smem, stream>>>(oat, wob, bo, (float*)d_out, 1.0f);
  }
}